// Round 7
// baseline (50.123 us; speedup 1.0000x reference)
//
#include <hip/hip_runtime.h>
#include <hip/hip_bf16.h>
#include <stdint.h>

typedef short bf16x8 __attribute__((ext_vector_type(8)));
typedef float f32x4  __attribute__((ext_vector_type(4)));

#define B_   32
#define CIN  32
#define COUT 64
#define H_   128
#define W_   128
#define HW   (H_ * W_)
#define T_   2            // output rows per block
#define RROWS 4           // staged input rows = T_+2
#define PXW  130          // padded width
#define SCW  68           // scratch row stride in words (16B-aligned, 2-way banks)

// s_waitcnt imm: vmcnt=63, expcnt=7, lgkmcnt=0  -> wait LDS only, NOT stores
#define WAIT_LGKM0() __builtin_amdgcn_s_waitcnt(0xC07F)

static __device__ __forceinline__ ushort f2bf(float v) {
    __hip_bfloat16 h = __float2bfloat16(v);
    return __builtin_bit_cast(ushort, h);
}

// ---------------------------------------------------------------------------
// Weight pack: [Cout][Cin][3][3] fp32 -> bf16 A-fragment order
// Wp[tap][ocg][lane][j] = W[ocg*16 + (lane&15)][8*(lane>>4)+j][ky][kx]
// ---------------------------------------------------------------------------
__global__ void prep_w_kernel(const float* __restrict__ wt, ushort* __restrict__ Wp) {
    int p = blockIdx.x * blockDim.x + threadIdx.x;
    if (p >= COUT * CIN * 9) return;  // 18432
    int j    = p & 7;
    int lane = (p >> 3) & 63;
    int g    = (p >> 9) & 3;
    int tap  = p >> 11;
    int oc   = g * 16 + (lane & 15);
    int cin  = (lane >> 4) * 8 + j;
    int ky   = tap / 3;
    int kx   = tap % 3;
    Wp[p] = f2bf(wt[(((size_t)oc * CIN + cin) * 3 + ky) * 3 + kx]);
}

// ---------------------------------------------------------------------------
// Fused conv: stage 4 padded rows (NCHW fp32 -> bf16 NHWC in LDS, swizzled),
// implicit-GEMM, then full-line epilogue (acc -> LDS scratch -> dwordx4).
// Scratch is OVERLAID on the staging buffer (dead after compute; extra
// barrier separates phases) -> LDS 33.3 KB -> 4 blocks/CU.
// Epilogue waits are lgkmcnt-only so global stores drain asynchronously.
// ---------------------------------------------------------------------------
__global__ __launch_bounds__(256, 4) void conv_fused_kernel(
    const float* __restrict__ in, const ushort* __restrict__ Wp,
    float* __restrict__ out) {
    __shared__ ushort lds[RROWS * PXW * 32];     // 33,280 B (staging + scratch)

    int hw_blk  = blockIdx.x;
    int logical = (hw_blk & 7) * 256 + (hw_blk >> 3);   // grid = 2048 = 8*256
    int b   = logical >> 6;          // /64
    int h0  = (logical & 63) * T_;
    int tid = threadIdx.x;

    // ---- stage: thread = one (row, px) column, loop 32 channels ----
    for (int i = tid; i < RROWS * PXW; i += 256) {
        int r  = i / PXW;
        int px = i - r * PXW;
        int gy = h0 + r - 1;
        bf16x8 v[4];
        if (gy >= 0 && gy < H_ && px >= 1 && px <= W_) {
            const float* src = in + ((size_t)b * CIN * H_ + gy) * W_ + (px - 1);
#pragma unroll
            for (int q = 0; q < 4; ++q)
#pragma unroll
                for (int j = 0; j < 8; ++j)
                    v[q][j] = (short)f2bf(src[(size_t)(q * 8 + j) * HW]);
        } else {
#pragma unroll
            for (int q = 0; q < 4; ++q)
#pragma unroll
                for (int j = 0; j < 8; ++j)
                    v[q][j] = 0;
        }
        uint32_t base_byte = (uint32_t)i * 64;
        uint32_t sw = ((uint32_t)(px >> 1) & 3u) << 4;
#pragma unroll
        for (int q = 0; q < 4; ++q)
            *(bf16x8*)((char*)lds + base_byte + (((uint32_t)q << 4) ^ sw)) = v[q];
    }
    __syncthreads();

    // ---- compute: wave = (row = wid>>1, px half = wid&1), 64 oc x 64 px ----
    int wid  = tid >> 6;
    int lane = tid & 63;
    int llo  = lane & 15;
    int lhi  = lane >> 4;
    int row  = wid >> 1;            // 0..1
    int px0  = (wid & 1) * 64;
    int h    = h0 + row;

    f32x4 acc[4][4];
#pragma unroll
    for (int g = 0; g < 4; ++g)
#pragma unroll
        for (int nf = 0; nf < 4; ++nf) {
            acc[g][nf][0] = 0.f; acc[g][nf][1] = 0.f;
            acc[g][nf][2] = 0.f; acc[g][nf][3] = 0.f;
        }

#pragma unroll
    for (int tap = 0; tap < 9; ++tap) {
        int dy = tap / 3;
        int dx = tap % 3;
        int rbase = (row + dy) * PXW;
        bf16x8 Af[4];
#pragma unroll
        for (int g = 0; g < 4; ++g)
            Af[g] = *(const bf16x8*)(Wp + ((size_t)(tap * 4 + g) * 64 + lane) * 8);
#pragma unroll
        for (int nf = 0; nf < 4; ++nf) {
            int px = px0 + nf * 16 + llo + dx;
            uint32_t byte = (uint32_t)(rbase + px) * 64u +
                            (((uint32_t)lhi << 4) ^ ((((uint32_t)px >> 1) & 3u) << 4));
            bf16x8 Bf = *(const bf16x8*)((const char*)lds + byte);
#pragma unroll
            for (int g = 0; g < 4; ++g)
                acc[g][nf] = __builtin_amdgcn_mfma_f32_16x16x32_bf16(Af[g], Bf, acc[g][nf], 0, 0, 0);
        }
    }

    // staging buffer is dead now; re-use it as per-wave f32 scratch
    __syncthreads();

    // ---- epilogue: per-wave LDS transpose -> full-line dwordx4 stores ----
    // acc[g][nf][r] is (oc' = lhi*4+r, px' = nf*16+llo). Readback: oc'=j*4+lhi,
    // px' = llo*4..+3 -> f32x4; 16 lanes cover 256B contiguous (full lines).
    float* myscr = (float*)lds + wid * 16 * SCW;
    float* obase = out + (size_t)b * COUT * HW + (size_t)h * W_ + px0;
#pragma unroll
    for (int g = 0; g < 4; ++g) {
#pragma unroll
        for (int nf = 0; nf < 4; ++nf)
#pragma unroll
            for (int r = 0; r < 4; ++r)
                myscr[(lhi * 4 + r) * SCW + nf * 16 + llo] = acc[g][nf][r];
        WAIT_LGKM0();                    // scratch writes visible (LDS only)
#pragma unroll
        for (int j = 0; j < 4; ++j) {
            int ocp = j * 4 + lhi;       // 0..15
            f32x4 vv = *(const f32x4*)(myscr + ocp * SCW + llo * 4);
            int oc = g * 16 + ocp;
            *(f32x4*)(obase + (size_t)oc * HW + llo * 4) = vv;
        }
        WAIT_LGKM0();                    // LDS reads done before scratch overwrite
    }
}

// ---------------------------------------------------------------------------
// Fallback: naive fp32 direct conv (only if workspace is too small for Wp)
// ---------------------------------------------------------------------------
__global__ void conv_naive_kernel(const float* __restrict__ in,
                                  const float* __restrict__ wt,
                                  float* __restrict__ out) {
    int idx = blockIdx.x * blockDim.x + threadIdx.x;
    if (idx >= B_ * COUT * HW) return;
    int w  = idx & 127;
    int h  = (idx >> 7) & 127;
    int oc = (idx >> 14) & 63;
    int b  = idx >> 20;
    float s = 0.f;
    for (int c = 0; c < CIN; ++c)
        for (int ky = 0; ky < 3; ++ky) {
            int y = h + ky - 1;
            if ((unsigned)y >= (unsigned)H_) continue;
            for (int kx = 0; kx < 3; ++kx) {
                int x = w + kx - 1;
                if ((unsigned)x >= (unsigned)W_) continue;
                s += in[((size_t)(b * CIN + c) * H_ + y) * W_ + x] *
                     wt[(((size_t)oc * CIN + c) * 3 + ky) * 3 + kx];
            }
        }
    out[idx] = s;
}

extern "C" void kernel_launch(void* const* d_in, const int* in_sizes, int n_in,
                              void* d_out, int out_size, void* d_ws, size_t ws_size,
                              hipStream_t stream) {
    const float* in = (const float*)d_in[0];
    const float* wt = (const float*)d_in[1];
    float* out = (float*)d_out;

    size_t Wp_bytes = (size_t)COUT * CIN * 9 * 2;   // 36,864

    if (ws_size >= Wp_bytes) {
        ushort* Wp = (ushort*)d_ws;
        prep_w_kernel<<<(COUT * CIN * 9 + 255) / 256, 256, 0, stream>>>(wt, Wp);
        conv_fused_kernel<<<B_ * (H_ / T_), 256, 0, stream>>>(in, Wp, out);
    } else {
        int total = B_ * COUT * HW;
        conv_naive_kernel<<<(total + 255) / 256, 256, 0, stream>>>(in, wt, out);
    }
}